// Round 4
// baseline (2447.345 us; speedup 1.0000x reference)
//
#include <hip/hip_runtime.h>
#include <hip/hip_bf16.h>

#define SS 256
#define RR 512
#define DD 256
#define HH 8

typedef __attribute__((ext_vector_type(8))) short s8;
typedef __attribute__((ext_vector_type(4))) float f4;

__device__ __forceinline__ unsigned short f2bf(float f) {
    union { unsigned int u; float f; } v; v.f = f;
    return (unsigned short)((v.u + 0x7FFFu + ((v.u >> 16) & 1u)) >> 16);
}

// 8 fp32 -> 8 bf16 (RNE, packed cvt)
__device__ __forceinline__ s8 pack8(f4 a, f4 b) {
    union { s8 v; __hip_bfloat162 h[4]; } u;
    u.h[0] = __float22bfloat162_rn(make_float2(a.x, a.y));
    u.h[1] = __float22bfloat162_rn(make_float2(a.z, a.w));
    u.h[2] = __float22bfloat162_rn(make_float2(b.x, b.y));
    u.h[3] = __float22bfloat162_rn(make_float2(b.z, b.w));
    return u.v;
}

// ---------------------------------------------------------------------------
// Kernel 1: per (r, h) block. LN + Q/K/V/G projections + softmax(QK^T)V * gate
// Inputs fp32; MFMA operands converted to bf16 on the fly.
// Plain row-major LDS layouts (correctness anchor):
//   scr  per wave (4096 shorts): Mn [16 s][256 d] -> Q [16][32] -> P [16][256]
//   Kb   (8192 shorts):  K   [256 s][32 c]
//   Vtb  (8192 shorts):  V^T [32 c][256 s]
// MFMA 16x16x32 bf16 layouts (HW-verified):
//   A-frag: lane(quad=l>>4, m16=l&15) holds A[m=m16][k=quad*8+j]
//   B-frag: lane holds B[n=m16][k=quad*8+j]
//   C/D   : (row=quad*4+reg, col=m16)
// Note: every MFMA reads BOTH operands through the same assumed k-order, so
// the result is invariant to the true intra-fragment k-permutation.
// ---------------------------------------------------------------------------
__global__ __launch_bounds__(256) void attn_kernel(
    const float* __restrict__ Mraw,
    const float* __restrict__ lnsc,
    const float* __restrict__ lnbi,
    const float* __restrict__ Wq,
    const float* __restrict__ Wk,
    const float* __restrict__ Wv,
    const float* __restrict__ Wg,
    const float* __restrict__ bg,
    unsigned short* __restrict__ go)
{
    __shared__ unsigned short lds[32768];
    const int r    = blockIdx.x;   // grid (RR, HH): same-r blocks -> same XCD
    const int h    = blockIdx.y;
    const int tid  = threadIdx.x;
    const int wave = tid >> 6;
    const int lane = tid & 63;
    const int quad = lane >> 4;
    const int m16  = lane & 15;

    unsigned short* scr = lds + wave * 4096;
    unsigned short* Kb  = lds + 16384;
    unsigned short* Vtb = lds + 24576;

    float bgv[2];
    bgv[0] = bg[h * 32 + m16];
    bgv[1] = bg[h * 32 + 16 + m16];

    s8 qfrag[4];
    float garr[4][2][4];

    const int row = lane >> 2;  // 0..15 : row within s-tile for LN staging
    const int l4  = lane & 3;   // 4 lanes cooperate per row

    // ================= phase 1: LN + projections =================
    #pragma unroll
    for (int i = 0; i < 4; ++i) {
        const int st = wave + 4 * i;       // s-tile owned by this wave
        const int s0 = st * 16;

        // ---- LN of 16 rows (fp32 in) -> plain [16][256] bf16 tile in scr
        const float* mrow = Mraw + ((size_t)(s0 + row) * RR + r) * DD;
        float sum = 0.f, ss2 = 0.f;
        #pragma unroll
        for (int o = 0; o < 8; ++o) {
            const int d0 = (o * 4 + l4) * 8;
            f4 a = *(const f4*)(mrow + d0);
            f4 b = *(const f4*)(mrow + d0 + 4);
            sum += a.x + a.y + a.z + a.w + b.x + b.y + b.z + b.w;
            ss2 += a.x*a.x + a.y*a.y + a.z*a.z + a.w*a.w
                 + b.x*b.x + b.y*b.y + b.z*b.z + b.w*b.w;
        }
        sum += __shfl_xor(sum, 1); sum += __shfl_xor(sum, 2);
        ss2 += __shfl_xor(ss2, 1); ss2 += __shfl_xor(ss2, 2);
        const float mu   = sum * (1.f / 256.f);
        const float rstd = rsqrtf(ss2 * (1.f / 256.f) - mu * mu + 1e-5f);
        #pragma unroll
        for (int o = 0; o < 8; ++o) {
            const int d0 = (o * 4 + l4) * 8;
            f4 a  = *(const f4*)(mrow + d0);
            f4 b  = *(const f4*)(mrow + d0 + 4);
            f4 s0v = *(const f4*)(lnsc + d0);
            f4 s1v = *(const f4*)(lnsc + d0 + 4);
            f4 b0v = *(const f4*)(lnbi + d0);
            f4 b1v = *(const f4*)(lnbi + d0 + 4);
            f4 na, nb;
            na.x = (a.x - mu) * rstd * s0v.x + b0v.x;
            na.y = (a.y - mu) * rstd * s0v.y + b0v.y;
            na.z = (a.z - mu) * rstd * s0v.z + b0v.z;
            na.w = (a.w - mu) * rstd * s0v.w + b0v.w;
            nb.x = (b.x - mu) * rstd * s1v.x + b1v.x;
            nb.y = (b.y - mu) * rstd * s1v.y + b1v.y;
            nb.z = (b.z - mu) * rstd * s1v.z + b1v.z;
            nb.w = (b.w - mu) * rstd * s1v.w + b1v.w;
            *(s8*)(scr + row * 256 + d0) = pack8(na, nb);
        }
        __syncthreads();

        // ---- 8 MFMA accumulators: {Q,K,V,G} x 2 c-tiles, K=256 in 8 steps
        f4 aq[2] = {{0,0,0,0},{0,0,0,0}}, ak[2] = {{0,0,0,0},{0,0,0,0}};
        f4 av[2] = {{0,0,0,0},{0,0,0,0}}, ag[2] = {{0,0,0,0},{0,0,0,0}};
        #pragma unroll
        for (int ks = 0; ks < 8; ++ks) {
            s8 a = *(const s8*)(scr + m16 * 256 + ks * 32 + quad * 8);
            const int ko = ks * 32 + quad * 8;
            #pragma unroll
            for (int ct = 0; ct < 2; ++ct) {
                const size_t wrow = (size_t)(h * 32 + ct * 16 + m16) * DD + ko;
                s8 bq = pack8(*(const f4*)(Wq + wrow), *(const f4*)(Wq + wrow + 4));
                s8 bk = pack8(*(const f4*)(Wk + wrow), *(const f4*)(Wk + wrow + 4));
                s8 bv = pack8(*(const f4*)(Wv + wrow), *(const f4*)(Wv + wrow + 4));
                s8 bw = pack8(*(const f4*)(Wg + wrow), *(const f4*)(Wg + wrow + 4));
                aq[ct] = __builtin_amdgcn_mfma_f32_16x16x32_bf16(a, bq, aq[ct], 0, 0, 0);
                ak[ct] = __builtin_amdgcn_mfma_f32_16x16x32_bf16(a, bk, ak[ct], 0, 0, 0);
                av[ct] = __builtin_amdgcn_mfma_f32_16x16x32_bf16(a, bv, av[ct], 0, 0, 0);
                ag[ct] = __builtin_amdgcn_mfma_f32_16x16x32_bf16(a, bw, ag[ct], 0, 0, 0);
            }
        }
        __syncthreads();

        // ---- Q: scale, C-layout -> plain [16 q][32 c] in scr, reload as A-frag
        #pragma unroll
        for (int ct = 0; ct < 2; ++ct)
            #pragma unroll
            for (int j = 0; j < 4; ++j)
                scr[(quad * 4 + j) * 32 + ct * 16 + m16] =
                    f2bf(aq[ct][j] * 0.17677669529663687f);
        __syncthreads();
        qfrag[i] = *(const s8*)(scr + m16 * 32 + quad * 8);

        // ---- K plain [256][32], V^T plain [32][256]; gate into registers
        #pragma unroll
        for (int ct = 0; ct < 2; ++ct) {
            #pragma unroll
            for (int j = 0; j < 4; ++j) {
                const int s = s0 + quad * 4 + j;
                Kb[s * 32 + ct * 16 + m16]     = f2bf(ak[ct][j]);
                Vtb[(ct * 16 + m16) * 256 + s] = f2bf(av[ct][j]);
                garr[i][ct][j] = 1.f / (1.f + __expf(-(ag[ct][j] + bgv[ct])));
            }
        }
        __syncthreads();
    }
    __syncthreads();

    // ================= phase 2: attention per owned q-tile =================
    #pragma unroll
    for (int i = 0; i < 4; ++i) {
        const int st = wave + 4 * i;
        const int s0 = st * 16;

        // logits [16 q x 256 k] in C-layout registers
        f4 lg[16];
        #pragma unroll
        for (int t = 0; t < 16; ++t) {
            s8 b = *(const s8*)(Kb + (t * 16 + m16) * 32 + quad * 8);
            f4 z = {0, 0, 0, 0};
            lg[t] = __builtin_amdgcn_mfma_f32_16x16x32_bf16(qfrag[i], b, z, 0, 0, 0);
        }
        // softmax: row (quad*4+j) lives in the 16 lanes of this quad
        #pragma unroll
        for (int j = 0; j < 4; ++j) {
            float mx = lg[0][j];
            #pragma unroll
            for (int t = 1; t < 16; ++t) mx = fmaxf(mx, lg[t][j]);
            mx = fmaxf(mx, __shfl_xor(mx, 1));
            mx = fmaxf(mx, __shfl_xor(mx, 2));
            mx = fmaxf(mx, __shfl_xor(mx, 4));
            mx = fmaxf(mx, __shfl_xor(mx, 8));
            float sm = 0.f;
            #pragma unroll
            for (int t = 0; t < 16; ++t) {
                float e = __expf(lg[t][j] - mx); lg[t][j] = e; sm += e;
            }
            sm += __shfl_xor(sm, 1); sm += __shfl_xor(sm, 2);
            sm += __shfl_xor(sm, 4); sm += __shfl_xor(sm, 8);
            const float inv = 1.f / sm;
            #pragma unroll
            for (int t = 0; t < 16; ++t) lg[t][j] *= inv;
        }
        // P -> plain [16 q][256 k] in scr
        #pragma unroll
        for (int t = 0; t < 16; ++t)
            #pragma unroll
            for (int j = 0; j < 4; ++j)
                scr[(quad * 4 + j) * 256 + t * 16 + m16] = f2bf(lg[t][j]);
        __syncthreads();
        // O = P @ V, then gate and store (bf16 to ws)
        #pragma unroll
        for (int ct = 0; ct < 2; ++ct) {
            f4 o = {0, 0, 0, 0};
            #pragma unroll
            for (int ks = 0; ks < 8; ++ks) {
                s8 a = *(const s8*)(scr + m16 * 256 + ks * 32 + quad * 8);
                s8 b = *(const s8*)(Vtb + (ct * 16 + m16) * 256 + ks * 32 + quad * 8);
                o = __builtin_amdgcn_mfma_f32_16x16x32_bf16(a, b, o, 0, 0, 0);
            }
            #pragma unroll
            for (int j = 0; j < 4; ++j) {
                const int s = s0 + quad * 4 + j;
                go[((size_t)r * SS + s) * DD + h * 32 + ct * 16 + m16] =
                    f2bf(o[j] * garr[i][ct][j]);
            }
        }
        __syncthreads();
    }
}

// ---------------------------------------------------------------------------
// Kernel 2: out[s,r,:] = Mraw[s,r,:] + bo + (gate*o)[r,s,:] @ Wo^T
// go bf16 (ws), Wo/bo/Mraw fp32, out FP32 (reference output dtype).
// ---------------------------------------------------------------------------
__global__ __launch_bounds__(256) void outproj_kernel(
    const unsigned short* __restrict__ go,
    const float* __restrict__ Wo,
    const float* __restrict__ bo,
    const float* __restrict__ Mraw,
    float* __restrict__ out)
{
    const int tid  = threadIdx.x;
    const int wave = tid >> 6;
    const int lane = tid & 63;
    const int quad = lane >> 4;
    const int m16  = lane & 15;
    const int g0   = (blockIdx.x * 4 + wave) * 16;

    s8 afr[8];
    #pragma unroll
    for (int ks = 0; ks < 8; ++ks)
        afr[ks] = *(const s8*)(go + (size_t)(g0 + m16) * DD + ks * 32 + quad * 8);

    #pragma unroll 2
    for (int nt = 0; nt < 16; ++nt) {
        f4 acc = {0, 0, 0, 0};
        #pragma unroll
        for (int ks = 0; ks < 8; ++ks) {
            const size_t wrow = (size_t)(nt * 16 + m16) * DD + ks * 32 + quad * 8;
            s8 b = pack8(*(const f4*)(Wo + wrow), *(const f4*)(Wo + wrow + 4));
            acc = __builtin_amdgcn_mfma_f32_16x16x32_bf16(afr[ks], b, acc, 0, 0, 0);
        }
        const float bov = bo[nt * 16 + m16];
        #pragma unroll
        for (int j = 0; j < 4; ++j) {
            const int g  = g0 + quad * 4 + j;   // g = r*S + s
            const int rr = g >> 8;
            const int sA = g & 255;
            const size_t oaddr = ((size_t)sA * RR + rr) * DD + nt * 16 + m16;
            out[oaddr] = acc[j] + bov + Mraw[oaddr];
        }
    }
}

// ws-too-small sentinel (absmax ~1024 under fp32 readback)
__global__ void sentinel_ws_kernel(unsigned int* out32) {
    out32[0] = 0x44800000u;   // fp32 1024.0
}

extern "C" void kernel_launch(void* const* d_in, const int* in_sizes, int n_in,
                              void* d_out, int out_size, void* d_ws, size_t ws_size,
                              hipStream_t stream) {
    const float* Mraw = (const float*)d_in[0];
    const float* lnsc = (const float*)d_in[1];
    const float* lnbi = (const float*)d_in[2];
    const float* Wq   = (const float*)d_in[3];
    const float* Wk   = (const float*)d_in[4];
    const float* Wv   = (const float*)d_in[5];
    const float* Wg   = (const float*)d_in[6];
    const float* bg   = (const float*)d_in[7];
    const float* Wo   = (const float*)d_in[8];
    const float* bo   = (const float*)d_in[9];
    float* out = (float*)d_out;
    unsigned short* go = (unsigned short*)d_ws;   // [R,S,256] bf16 = 64 MiB

    const size_t need = (size_t)RR * SS * DD * 2;
    if (ws_size < need) {
        sentinel_ws_kernel<<<1, 1, 0, stream>>>((unsigned int*)d_out);
        return;
    }

    dim3 g1(RR, HH);
    attn_kernel<<<g1, 256, 0, stream>>>(Mraw, lnsc, lnbi, Wq, Wk, Wv, Wg, bg, go);
    outproj_kernel<<<(RR * SS) / 64, 256, 0, stream>>>(go, Wo, bo, Mraw, out);
}